// Round 2
// baseline (1721.637 us; speedup 1.0000x reference)
//
#include <hip/hip_runtime.h>
#include <hip/hip_bf16.h>

#define VOCAB     151936
#define BEAM      3
#define TOPK      3
#define SAVE_LEN  10
#define NUM_KV    32
#define KV_CHUNK  (8 * 2048 * 128)      // floats per (k, beam) slice = 2,097,152
#define KV_CHUNK4 (KV_CHUNK / 4)        // 524,288 float4 = 2^19

// better(a,b): jax top_k ordering — descending value, tie -> lower index
__device__ __forceinline__ bool better(float av, int ai, float bv, int bi) {
    return (av > bv) || (av == bv && ai < bi);
}

// ---------------------------------------------------------------------------
// Kernel A: per-beam max + top-3 of s = logits*rp, then logsumexp.
// One block per beam, 256 threads, two passes (inputs are L2-resident).
// ---------------------------------------------------------------------------
__global__ __launch_bounds__(256)
void topk_softmax_kernel(const float* __restrict__ logits,
                         const float* __restrict__ rp,
                         float* __restrict__ ws_topv,
                         int*   __restrict__ ws_topi) {
    const int b   = blockIdx.x;
    const int tid = threadIdx.x;
    const float* L = logits + (size_t)b * VOCAB;
    const float* R = rp     + (size_t)b * VOCAB;

    float m = -INFINITY;
    float tv[3] = {-INFINITY, -INFINITY, -INFINITY};
    int   ti[3] = {0x7fffffff, 0x7fffffff, 0x7fffffff};

    for (int v = tid; v < VOCAB; v += 256) {
        float s = L[v] * R[v];
        m = fmaxf(m, s);
        if (better(s, v, tv[2], ti[2])) {
            if (better(s, v, tv[0], ti[0])) {
                tv[2]=tv[1]; ti[2]=ti[1]; tv[1]=tv[0]; ti[1]=ti[0]; tv[0]=s; ti[0]=v;
            } else if (better(s, v, tv[1], ti[1])) {
                tv[2]=tv[1]; ti[2]=ti[1]; tv[1]=s; ti[1]=v;
            } else {
                tv[2]=s; ti[2]=v;
            }
        }
    }

    __shared__ float red[256];
    red[tid] = m; __syncthreads();
    for (int s = 128; s > 0; s >>= 1) {
        if (tid < s) red[tid] = fmaxf(red[tid], red[tid + s]);
        __syncthreads();
    }
    const float M = red[0];
    __syncthreads();

    // pass 2: sum exp(s - M)
    float sum = 0.f;
    for (int v = tid; v < VOCAB; v += 256) {
        float s = L[v] * R[v];
        sum += expf(s - M);
    }
    red[tid] = sum; __syncthreads();
    for (int s = 128; s > 0; s >>= 1) {
        if (tid < s) red[tid] += red[tid + s];
        __syncthreads();
    }
    const float lse = M + logf(red[0]);
    __syncthreads();

    // tree-merge per-thread top-3 lists
    __shared__ float sv[256][3];
    __shared__ int   si[256][3];
    for (int j = 0; j < 3; j++) { sv[tid][j] = tv[j]; si[tid][j] = ti[j]; }
    __syncthreads();
    for (int s = 128; s > 0; s >>= 1) {
        if (tid < s) {
            float av[3], bv[3]; int ai[3], bi[3];
            for (int j = 0; j < 3; j++) {
                av[j] = sv[tid][j];     ai[j] = si[tid][j];
                bv[j] = sv[tid + s][j]; bi[j] = si[tid + s][j];
            }
            float ov[3]; int oi[3];
            int ia = 0, ib = 0;
            for (int j = 0; j < 3; j++) {
                if (better(av[ia], ai[ia], bv[ib], bi[ib])) {
                    ov[j] = av[ia]; oi[j] = ai[ia]; ia++;
                } else {
                    ov[j] = bv[ib]; oi[j] = bi[ib]; ib++;
                }
            }
            for (int j = 0; j < 3; j++) { sv[tid][j] = ov[j]; si[tid][j] = oi[j]; }
        }
        __syncthreads();
    }
    if (tid == 0) {
        for (int j = 0; j < 3; j++) {
            ws_topv[b * 3 + j] = sv[0][j] - lse;   // log_softmax value of winner
            ws_topi[b * 3 + j] = si[0][j];
        }
    }
}

// ---------------------------------------------------------------------------
// Kernel B: 9-way top-3 beam selection + all tiny outputs. One thread.
// ---------------------------------------------------------------------------
__global__ void select_beams_kernel(const float* __restrict__ ws_topv,
                                    const int*   __restrict__ ws_topi,
                                    const float* __restrict__ prev,      // (BEAM,1)
                                    const int*   __restrict__ save_id,   // (BEAM,SAVE_LEN)
                                    float* __restrict__ out_tbi,         // 3
                                    float* __restrict__ out_save,        // 3*(SAVE_LEN+1)
                                    float* __restrict__ out_prob,        // 3
                                    float* __restrict__ out_maxidx,      // 1
                                    int*   __restrict__ ws_beam,
                                    int*   __restrict__ ws_tbi) {
    float cp[9];
    for (int j = 0; j < 9; j++) cp[j] = ws_topv[j] + prev[j / 3];

    bool used[9] = {false,false,false,false,false,false,false,false,false};
    for (int t = 0; t < 3; t++) {
        int best = -1;
        for (int j = 0; j < 9; j++) {
            if (used[j]) continue;
            if (best < 0 || cp[j] > cp[best]) best = j;  // strict > keeps lower flat idx on tie
        }
        used[best] = true;
        const int f  = best;
        const int bi = f / 3;
        const int vi = ws_topi[f];
        ws_beam[t] = bi;
        ws_tbi[t]  = vi;
        out_tbi[t]  = (float)vi;
        out_prob[t] = cp[f];
        for (int j = 0; j < SAVE_LEN; j++)
            out_save[t * (SAVE_LEN + 1) + j] = (float)save_id[bi * SAVE_LEN + j];
        out_save[t * (SAVE_LEN + 1) + SAVE_LEN] = (float)vi;
    }
    out_maxidx[0] = out_tbi[0];
}

// ---------------------------------------------------------------------------
// Kernel C: rp gather + fused .at[].multiply scatter (duplicate-safe).
// grid = (ceil(V/256), BEAM)
// ---------------------------------------------------------------------------
__global__ __launch_bounds__(256)
void rp_gather_kernel(const float* __restrict__ rp_in,
                      const int*   __restrict__ batch_indices,
                      const float* __restrict__ penalty,
                      const int*   __restrict__ ws_beam,
                      const int*   __restrict__ ws_tbi,
                      float* __restrict__ rp_out) {
    const int b = blockIdx.y;
    const int v = blockIdx.x * 256 + threadIdx.x;
    if (v >= VOCAB) return;
    float val = rp_in[(size_t)ws_beam[b] * VOCAB + v];
    const float p = penalty[0];
#pragma unroll
    for (int i = 0; i < 3; i++)
        if (batch_indices[i] == b && ws_tbi[i] == v) val *= p;
    rp_out[(size_t)b * VOCAB + v] = val;
}

// ---------------------------------------------------------------------------
// Kernel D: kv_cache beam gather — the 1.6 GB streaming copy.
// Thread handles one (k, off) float4 slot and writes all 3 beams, deduping
// source reads in registers (beam_index is grid-uniform -> no divergence).
// ---------------------------------------------------------------------------
__global__ __launch_bounds__(256)
void kv_gather_kernel(const float4* __restrict__ src,
                      const int*    __restrict__ ws_beam,
                      float4* __restrict__ dst) {
    const int b0 = ws_beam[0], b1 = ws_beam[1], b2 = ws_beam[2];
    const long long total  = (long long)NUM_KV * KV_CHUNK4;   // 16,777,216
    const long long stride = (long long)gridDim.x * blockDim.x;
    for (long long i = (long long)blockIdx.x * blockDim.x + threadIdx.x;
         i < total; i += stride) {
        const int       k   = (int)(i >> 19);              // KV_CHUNK4 = 2^19
        const long long off = i & (KV_CHUNK4 - 1);
        const float4* sbase = src + (long long)k * 3 * KV_CHUNK4 + off;
        float4* dbase       = dst + (long long)k * 3 * KV_CHUNK4 + off;

        float4 x0 = sbase[(long long)b0 * KV_CHUNK4];
        float4 x1 = (b1 == b0) ? x0 : sbase[(long long)b1 * KV_CHUNK4];
        float4 x2 = (b2 == b0) ? x0 : ((b2 == b1) ? x1 : sbase[(long long)b2 * KV_CHUNK4]);

        dbase[0]                       = x0;
        dbase[(long long)KV_CHUNK4]    = x1;
        dbase[2ll * KV_CHUNK4]         = x2;
    }
}

// ---------------------------------------------------------------------------
extern "C" void kernel_launch(void* const* d_in, const int* in_sizes, int n_in,
                              void* d_out, int out_size, void* d_ws, size_t ws_size,
                              hipStream_t stream) {
    const float* kv            = (const float*)d_in[0];
    const float* logits        = (const float*)d_in[1];
    const int*   save_id       = (const int*)  d_in[2];
    const float* rp            = (const float*)d_in[3];
    const float* prev          = (const float*)d_in[4];
    const int*   batch_indices = (const int*)  d_in[5];
    const float* penalty       = (const float*)d_in[6];

    float* out        = (float*)d_out;
    float* out_kv     = out;                                   // 201,326,592
    float* out_tbi    = out_kv + (long long)NUM_KV * BEAM * KV_CHUNK; // +3
    float* out_save   = out_tbi + BEAM;                        // +33
    float* out_rp     = out_save + BEAM * (SAVE_LEN + 1);      // +455,808
    float* out_prob   = out_rp + (long long)BEAM * VOCAB;      // +3
    float* out_maxidx = out_prob + BEAM;                       // +1

    float* ws_topv = (float*)d_ws;            // 9 floats
    int*   ws_topi = (int*)(ws_topv + 9);     // 9 ints
    int*   ws_beam = ws_topi + 9;             // 3 ints
    int*   ws_tbi  = ws_beam + 3;             // 3 ints

    topk_softmax_kernel<<<BEAM, 256, 0, stream>>>(logits, rp, ws_topv, ws_topi);
    select_beams_kernel<<<1, 1, 0, stream>>>(ws_topv, ws_topi, prev, save_id,
                                             out_tbi, out_save, out_prob, out_maxidx,
                                             ws_beam, ws_tbi);
    dim3 gridC((VOCAB + 255) / 256, BEAM);
    rp_gather_kernel<<<gridC, 256, 0, stream>>>(rp, batch_indices, penalty,
                                                ws_beam, ws_tbi, out_rp);
    kv_gather_kernel<<<8192, 256, 0, stream>>>((const float4*)kv, ws_beam,
                                               (float4*)out_kv);
}